// Round 10
// baseline (828.554 us; speedup 1.0000x reference)
//
#include <hip/hip_runtime.h>
#include <math.h>

#define B_   8
#define S_   1024
#define HDIM 768
#define FDIM 32
#define KDIM 800
#define D_   64
#define KSTEPS 25
// Instrumentation: repeat counts chosen to push each dispatch above the
// ~184us fill dispatches so rocprof top-5 shows OUR counters. Revert next round.
#define K1_REPS 16
#define K2_REPS 4

constexpr float NEGV = -1000000000000.0f;

typedef __attribute__((ext_vector_type(8))) short short8;
typedef __attribute__((ext_vector_type(4))) float f32x4;

static __device__ __forceinline__ unsigned short f2bf(float f) {
    unsigned int x = __float_as_uint(f);
    unsigned int r = (x + 0x7fffu + ((x >> 16) & 1u)) >> 16;   // RNE
    return (unsigned short)r;
}
static __device__ __forceinline__ unsigned int pack2(float a, float b) {
    return (unsigned int)f2bf(a) | ((unsigned int)f2bf(b) << 16);
}

// ---------------------------------------------------------------------------
// k0: blocks 0..24: repack W1/W2 -> Wt bf16 + bv; blocks 25..32: rope table.
// (byte-identical R8)
// ---------------------------------------------------------------------------
__global__ __launch_bounds__(256) void k0_prep(
    const float* __restrict__ W1, const float* __restrict__ b1,
    const float* __restrict__ W2, const float* __restrict__ b2,
    unsigned short* __restrict__ Wt, float* __restrict__ bv,
    float2* __restrict__ rope)
{
    const int tid = threadIdx.x;
    if (blockIdx.x >= 25) {
        int e = (blockIdx.x - 25) * 256 + tid;
#pragma unroll
        for (int t = 0; t < 16; ++t, e += 2048) {
            const int s = e >> 5, i = e & 31;
            const float freq = exp2f(-(float)i * 0.4152410119f);
            float sv, cv;
            sincosf((float)s * freq, &sv, &cv);
            rope[e] = make_float2(cv, sv);
        }
        return;
    }

    __shared__ float shW[32][136];
    __shared__ float shW2[32][20];
    const int k0 = blockIdx.x << 5;
#pragma unroll
    for (int p = 0; p < 4; ++p) {
        const int flat = tid + (p << 8);
        const int kk = flat >> 5;
        const int c4 = (flat & 31) << 2;
        const float4 v = *(const float4*)(W1 + (size_t)(k0 + kk) * 128 + c4);
        shW[kk][c4 + 0] = v.x; shW[kk][c4 + 1] = v.y;
        shW[kk][c4 + 2] = v.z; shW[kk][c4 + 3] = v.w;
    }
    for (int i = tid; i < 576; i += 256)
        shW2[i / 18][i % 18] = W2[(size_t)k0 * 18 + i];
    __syncthreads();

    for (int i = tid; i < 768; i += 256) {
        const int tile = i >> 6, g = (i >> 4) & 3, col = i & 15;
        const int nc = tile * 16 + col;
        unsigned int pk[4];
#pragma unroll
        for (int h = 0; h < 4; ++h) {
            const int ka = g * 8 + 2 * h, kb = ka + 1;
            float a, b;
            if (nc < 64)       { a = shW[ka][2*nc];          b = shW[kb][2*nc]; }
            else if (nc < 128) { a = shW[ka][2*(nc-64)+1];   b = shW[kb][2*(nc-64)+1]; }
            else if (nc < 146) { a = shW2[ka][nc-128];       b = shW2[kb][nc-128]; }
            else               { a = 0.0f; b = 0.0f; }
            pk[h] = pack2(a, b);
        }
        *(uint4*)(Wt + ((size_t)blockIdx.x * 768 + i) * 8) =
            make_uint4(pk[0], pk[1], pk[2], pk[3]);
    }
    if (blockIdx.x == 0 && tid < 192) {
        float v = tid < 64  ? b1[2 * tid]
                : tid < 128 ? b1[2 * (tid - 64) + 1]
                : tid < 146 ? b2[tid - 128] : 0.0f;
        bv[tid] = v;
    }
}

// ---------------------------------------------------------------------------
// k1: R8 kernel wrapped in K1_REPS idempotent repeats (instrumentation).
// ---------------------------------------------------------------------------
__global__ __launch_bounds__(256) void k1_proj(
    const float* __restrict__ lhs, const float* __restrict__ hf,
    const unsigned short* __restrict__ Wt, const float* __restrict__ bv,
    const float2* __restrict__ rope,
    unsigned short* __restrict__ qw, unsigned short* __restrict__ kw,
    float* __restrict__ bias_t)
{
    __shared__ __align__(16) unsigned short st[2][832 * 8];
    __shared__ __align__(16) unsigned short repack[16][128];

    const int tid  = threadIdx.x;
    const int m0   = blockIdx.x << 4;
    const int lane = tid & 63;
    const int w    = tid >> 6;
    const int r16  = lane & 15;
    const int g    = lane >> 4;

    const int arow   = tid >> 3;
    const int akq    = (tid & 7) << 2;
    const int achunk = ((akq >> 3) << 4) + arow;
    const int ahalf  = (akq >> 2) & 1;

    float4 rA;
    uint4  rB[3];

    auto loadA = [&](int c) {
        if (tid < 128) {
            const int k = (c << 5) + akq;
            rA = (k < HDIM)
               ? *(const float4*)(lhs + (size_t)(m0 + arow) * HDIM + k)
               : *(const float4*)(hf  + (size_t)(m0 + arow) * FDIM + (k - HDIM));
        }
    };
    auto loadB = [&](int c) {
#pragma unroll
        for (int u = 0; u < 3; ++u) {
            const int i = tid + (u << 8);
            rB[u] = *(const uint4*)(Wt + ((size_t)c * 768 + i) * 8);
        }
    };
    auto commit = [&](int buf) {
        if (tid < 128)
            *(uint2*)&st[buf][achunk * 8 + ahalf * 4] =
                make_uint2(pack2(rA.x, rA.y), pack2(rA.z, rA.w));
#pragma unroll
        for (int u = 0; u < 3; ++u) {
            const int i = tid + (u << 8);
            *(uint4*)&st[buf][(64 + i) * 8] = rB[u];
        }
    };

    for (int rep = 0; rep < K1_REPS; ++rep) {
        __syncthreads();                   // prior rep's LDS use fully drained

        f32x4 acc[3];
        const f32x4 zero = {0.0f, 0.0f, 0.0f, 0.0f};
#pragma unroll
        for (int u = 0; u < 3; ++u) acc[u] = zero;

        loadA(0); loadB(0); commit(0);
        loadA(1); loadB(1);

        for (int c = 0; c < KSTEPS; ++c) {
            __syncthreads();
            const int buf = c & 1;
            const short8 af = *(const short8*)&st[buf][(g * 16 + r16) * 8];
#pragma unroll
            for (int u = 0; u < 3; ++u) {
                const int tile = w * 3 + u;
                const short8 bf =
                    *(const short8*)&st[buf][(64 + tile * 64 + g * 16 + r16) * 8];
                acc[u] = __builtin_amdgcn_mfma_f32_16x16x32_bf16(af, bf, acc[u], 0, 0, 0);
            }
            if (c + 1 < KSTEPS) {
                commit((c + 1) & 1);
                if (c + 2 < KSTEPS) { loadA(c + 2); loadB(c + 2); }
            }
        }

        const int bidx = m0 >> 10;
        const int s0   = m0 & (S_ - 1);
#pragma unroll
        for (int u = 0; u < 3; ++u) {
            const int tile = w * 3 + u;
            if (tile < 8) {
                const int jj  = (tile < 4 ? tile : tile - 4) * 16 + r16;
                const int fi  = jj >> 1;
                const float bvv = bv[tile * 16 + r16];
                const float sgn = (jj & 1) ? 1.0f : -1.0f;
                const float scl = (tile < 4) ? 0.125f : 1.0f;
                float x[4], p[4];
#pragma unroll
                for (int rr = 0; rr < 4; ++rr) x[rr] = acc[u][rr] + bvv;
#pragma unroll
                for (int rr = 0; rr < 4; ++rr) p[rr] = __shfl_xor(x[rr], 1, 64);
                const int cbase = (tile < 4 ? 0 : 64) + jj;
#pragma unroll
                for (int rr = 0; rr < 4; ++rr) {
                    const float2 cs = rope[((s0 + g * 4 + rr) << 5) + fi];
                    repack[g * 4 + rr][cbase] =
                        f2bf(fmaf(p[rr], sgn * cs.y, x[rr] * cs.x) * scl);
                }
            } else if (tile < 10) {
                const int cc = (tile - 8) * 16 + r16;
                if (cc < 18) {
                    const float bvv = bv[tile * 16 + r16];
                    f32x4 v;
#pragma unroll
                    for (int rr = 0; rr < 4; ++rr) v[rr] = (acc[u][rr] + bvv) * 0.5f;
                    *(f32x4*)(bias_t + (((size_t)(bidx * 18 + cc)) << 10) + s0 + g * 4) = v;
                }
            }
        }
        __syncthreads();
        {
            const int row = tid >> 4, seg = tid & 15;
            const uint4 v = *(const uint4*)&repack[row][seg * 8];
            if (seg < 8) *(uint4*)(qw + ((size_t)(m0 + row)) * D_ + seg * 8) = v;
            else         *(uint4*)(kw + ((size_t)(m0 + row)) * D_ + (seg - 8) * 8) = v;
        }
    }
}

// ---------------------------------------------------------------------------
// k2: R6/R8 fused kernel wrapped in K2_REPS idempotent repeats
// (instrumentation; staging re-done per rep since tbuf aliases qsm/ksm).
// ---------------------------------------------------------------------------
__global__ __launch_bounds__(256) void k2_logits(
    const unsigned short* __restrict__ qw, const unsigned short* __restrict__ kw,
    const float* __restrict__ bias_t, const int* __restrict__ mask,
    float* __restrict__ out)
{
    __shared__ __align__(16) char smem_u[64 * 66 * 4];
    __shared__ float bn[18][64];
    __shared__ float bm[18][64];
    __shared__ float mqf[64], mkf[64];
    unsigned short* qsm = (unsigned short*)smem_u;
    unsigned short* ksm = qsm + 64 * 64;
    float* tbuf = (float*)smem_u;

    const int tid = threadIdx.x;
    int bid;
    {
        const int i = blockIdx.x;
        bid = (i & 7) * 256 + (i >> 3);    // XCD-chunked: XCD x -> batch x
    }
    const int b   = bid >> 8;
    const int rem = bid & 255;
    const int m0  = (rem >> 4) << 6;
    const int n0  = (rem & 15) << 6;

    for (int rep = 0; rep < K2_REPS; ++rep) {
        __syncthreads();                   // prior rep's tbuf reads done

#pragma unroll
        for (int u = 0; u < 2; ++u) {
            const int idx = tid + (u << 8);
            const int row = idx >> 3;
            const int c8  = idx & 7;
            const int sb  = (row << 7) + ((c8 ^ (row & 7)) << 4);
            const uint4 vq = *(const uint4*)(qw + ((size_t)(b << 10) + m0 + row) * D_ + (c8 << 3));
            *(uint4*)((char*)qsm + sb) = vq;
            const uint4 vk = *(const uint4*)(kw + ((size_t)(b << 10) + n0 + row) * D_ + (c8 << 3));
            *(uint4*)((char*)ksm + sb) = vk;
        }
        for (int idx = tid; idx < 18 * 64; idx += 256) {
            const int c = idx >> 6;
            const int x = idx & 63;
            bn[c][x] = bias_t[(((size_t)(b * 18 + c)) << 10) + n0 + x];
            bm[c][x] = bias_t[(((size_t)(b * 18 + c)) << 10) + m0 + x];
        }
        if (tid < 64)        mqf[tid]      = (float)mask[b * S_ + m0 + tid];
        else if (tid < 128)  mkf[tid - 64] = (float)mask[b * S_ + n0 + (tid - 64)];
        __syncthreads();

        const int lane = tid & 63;
        const int w    = tid >> 6;
        const int wr   = w >> 1;
        const int wc   = w & 1;
        const int r16  = lane & 15;
        const int g    = lane >> 4;

        f32x4 acc[2][2];
        const f32x4 zero = {0.0f, 0.0f, 0.0f, 0.0f};
#pragma unroll
        for (int mi = 0; mi < 2; ++mi)
#pragma unroll
            for (int ni = 0; ni < 2; ++ni) acc[mi][ni] = zero;

#pragma unroll
        for (int ku = 0; ku < 2; ++ku) {
            short8 af[2], bf[2];
#pragma unroll
            for (int mi = 0; mi < 2; ++mi) {
                const int row  = wr * 32 + mi * 16 + r16;
                const int slot = ((ku << 2) + g) ^ (row & 7);
                af[mi] = *(const short8*)((const char*)qsm + (row << 7) + (slot << 4));
            }
#pragma unroll
            for (int ni = 0; ni < 2; ++ni) {
                const int row  = wc * 32 + ni * 16 + r16;
                const int slot = ((ku << 2) + g) ^ (row & 7);
                bf[ni] = *(const short8*)((const char*)ksm + (row << 7) + (slot << 4));
            }
#pragma unroll
            for (int mi = 0; mi < 2; ++mi)
#pragma unroll
                for (int ni = 0; ni < 2; ++ni)
                    acc[mi][ni] = __builtin_amdgcn_mfma_f32_16x16x32_bf16(
                        af[mi], bf[ni], acc[mi][ni], 0, 0, 0);
        }

        __syncthreads();
#pragma unroll
        for (int mi = 0; mi < 2; ++mi)
#pragma unroll
            for (int ni = 0; ni < 2; ++ni)
#pragma unroll
                for (int rr = 0; rr < 4; ++rr)
                    tbuf[(wr * 32 + mi * 16 + g * 4 + rr) * 66 +
                         wc * 32 + ni * 16 + r16] = acc[mi][ni][rr];
        __syncthreads();

        const int rb = tid >> 4;
        const int c4 = (tid & 15) << 2;
        const float fk0 = mkf[c4 + 0], fk1 = mkf[c4 + 1],
                    fk2 = mkf[c4 + 2], fk3 = mkf[c4 + 3];

        float  p[4][4], accp[4][4];
        size_t base[4];
#pragma unroll
        for (int i = 0; i < 4; ++i) {
            const int row = rb + (i << 4);
            const int rg  = m0 + row;
            const float fm = mqf[row];
            const f32x4 a = *(const f32x4*)&tbuf[row * 66 + c4];
            const float fkk[4] = {fk0, fk1, fk2, fk3};
#pragma unroll
            for (int j = 0; j < 4; ++j) {
                const float fk = fkk[j];
                const float pj = fm * fk;
                float ad = NEGV * ((1.0f - fm) * fk + (1.0f - fk));
                if (rg > n0 + c4 + j) ad += NEGV;
                p[i][j]    = pj;
                accp[i][j] = fmaf(a[j], pj, ad);
            }
            base[i] = (((size_t)(b * 9)) << 20) + ((size_t)rg << 10) + n0 + c4;
        }

#pragma unroll
        for (int t = 0; t < 9; ++t) {
            const f32x4 bnv = *(const f32x4*)&bn[2 * t][c4];
            const size_t toff = (size_t)t << 20;
#pragma unroll
            for (int i = 0; i < 4; ++i) {
                const float bmv = bm[2 * t + 1][rb + (i << 4)];
                f32x4 v;
#pragma unroll
                for (int j = 0; j < 4; ++j)
                    v[j] = fmaf(bnv[j] + bmv, p[i][j], accp[i][j]);
                *(f32x4*)(out + base[i] + toff) = v;
            }
        }
    }
}

extern "C" void kernel_launch(void* const* d_in, const int* in_sizes, int n_in,
                              void* d_out, int out_size, void* d_ws, size_t ws_size,
                              hipStream_t stream) {
    const float* lhs  = (const float*)d_in[0];
    const float* hf   = (const float*)d_in[1];
    const int*   mask = (const int*)  d_in[2];
    const float* W1   = (const float*)d_in[3];
    const float* b1   = (const float*)d_in[4];
    const float* W2   = (const float*)d_in[5];
    const float* b2   = (const float*)d_in[6];
    float* out = (float*)d_out;

    unsigned short* qw = (unsigned short*)d_ws;              // 1 MB
    unsigned short* kw = qw + (size_t)B_ * S_ * D_;          // 1 MB
    float* bias_t = (float*)((char*)d_ws + (4u << 20));      // 576 KB @ 4 MB
    unsigned short* Wt = (unsigned short*)((char*)d_ws + (8u << 20)); // 300 KB
    float* bv = (float*)((char*)d_ws + (9u << 20));          // 768 B
    float2* rope = (float2*)((char*)d_ws + (10u << 20));     // 256 KB @ 10 MB

    k0_prep<<<33, 256, 0, stream>>>(W1, b1, W2, b2, Wt, bv, rope);
    k1_proj<<<(B_ * S_) / 16, 256, 0, stream>>>(lhs, hf, Wt, bv, rope,
                                                qw, kw, bias_t);
    k2_logits<<<B_ * 16 * 16, 256, 0, stream>>>(qw, kw, bias_t, mask, out);
}

// Round 11
// 86.300 us; speedup vs baseline: 9.6008x; 9.6008x over previous
//
#include <hip/hip_runtime.h>
#include <math.h>

#define B_   8
#define S_   1024
#define HDIM 768
#define FDIM 32
#define KDIM 800
#define D_   64
#define KSTEPS 25

constexpr float NEGV = -1000000000000.0f;

typedef __attribute__((ext_vector_type(8))) short short8;
typedef __attribute__((ext_vector_type(4))) float f32x4;

static __device__ __forceinline__ unsigned short f2bf(float f) {
    unsigned int x = __float_as_uint(f);
    unsigned int r = (x + 0x7fffu + ((x >> 16) & 1u)) >> 16;   // RNE
    return (unsigned short)r;
}
static __device__ __forceinline__ unsigned int pack2(float a, float b) {
    return (unsigned int)f2bf(a) | ((unsigned int)f2bf(b) << 16);
}

union frag_cast { unsigned int u[4]; short8 s8; };

// ---------------------------------------------------------------------------
// k0: blocks 0..24: repack W1/W2 -> Wt bf16 (MFMA-frag chunk order) + bv.
//     blocks 25..32: rope table. (byte-identical R8)
// ---------------------------------------------------------------------------
__global__ __launch_bounds__(256) void k0_prep(
    const float* __restrict__ W1, const float* __restrict__ b1,
    const float* __restrict__ W2, const float* __restrict__ b2,
    unsigned short* __restrict__ Wt, float* __restrict__ bv,
    float2* __restrict__ rope)
{
    const int tid = threadIdx.x;
    if (blockIdx.x >= 25) {
        int e = (blockIdx.x - 25) * 256 + tid;
#pragma unroll
        for (int t = 0; t < 16; ++t, e += 2048) {
            const int s = e >> 5, i = e & 31;
            const float freq = exp2f(-(float)i * 0.4152410119f);
            float sv, cv;
            sincosf((float)s * freq, &sv, &cv);
            rope[e] = make_float2(cv, sv);
        }
        return;
    }

    __shared__ float shW[32][136];
    __shared__ float shW2[32][20];
    const int k0 = blockIdx.x << 5;
#pragma unroll
    for (int p = 0; p < 4; ++p) {
        const int flat = tid + (p << 8);
        const int kk = flat >> 5;
        const int c4 = (flat & 31) << 2;
        const float4 v = *(const float4*)(W1 + (size_t)(k0 + kk) * 128 + c4);
        shW[kk][c4 + 0] = v.x; shW[kk][c4 + 1] = v.y;
        shW[kk][c4 + 2] = v.z; shW[kk][c4 + 3] = v.w;
    }
    for (int i = tid; i < 576; i += 256)
        shW2[i / 18][i % 18] = W2[(size_t)k0 * 18 + i];
    __syncthreads();

    for (int i = tid; i < 768; i += 256) {
        const int tile = i >> 6, g = (i >> 4) & 3, col = i & 15;
        const int nc = tile * 16 + col;
        unsigned int pk[4];
#pragma unroll
        for (int h = 0; h < 4; ++h) {
            const int ka = g * 8 + 2 * h, kb = ka + 1;
            float a, b;
            if (nc < 64)       { a = shW[ka][2*nc];          b = shW[kb][2*nc]; }
            else if (nc < 128) { a = shW[ka][2*(nc-64)+1];   b = shW[kb][2*(nc-64)+1]; }
            else if (nc < 146) { a = shW2[ka][nc-128];       b = shW2[kb][nc-128]; }
            else               { a = 0.0f; b = 0.0f; }
            pk[h] = pack2(a, b);
        }
        *(uint4*)(Wt + ((size_t)blockIdx.x * 768 + i) * 8) =
            make_uint4(pk[0], pk[1], pk[2], pk[3]);
    }
    if (blockIdx.x == 0 && tid < 192) {
        float v = tid < 64  ? b1[2 * tid]
                : tid < 128 ? b1[2 * (tid - 64) + 1]
                : tid < 146 ? b2[tid - 128] : 0.0f;
        bv[tid] = v;
    }
}

// ---------------------------------------------------------------------------
// k1: LDS-FREE MFMA K-loop. Both operands stream global->reg (B from Wt is
// frag-layout uint4, wave-contiguous 1KB, L2-hit; A is 2 float4/lane + inline
// f2bf). 4-deep register double-buffer, zero barriers in the loop -> no
// vmcnt(0) drains; compiler emits counted per-reg waits. Epilogue unchanged.
// ---------------------------------------------------------------------------
__global__ __launch_bounds__(256) void k1_proj(
    const float* __restrict__ lhs, const float* __restrict__ hf,
    const unsigned short* __restrict__ Wt, const float* __restrict__ bv,
    const float2* __restrict__ rope,
    unsigned short* __restrict__ qw, unsigned short* __restrict__ kw,
    float* __restrict__ bias_t)
{
    __shared__ __align__(16) unsigned short repack[16][128];

    const int tid  = threadIdx.x;
    const int m0   = blockIdx.x << 4;
    const int lane = tid & 63;
    const int w    = tid >> 6;
    const int r16  = lane & 15;
    const int g    = lane >> 4;

    // per-lane A source row and B chunk base (chunk i = tile*64 + g*16 + r16)
    const float* arow = lhs + (size_t)(m0 + r16) * HDIM;
    const float* hrow = hf  + (size_t)(m0 + r16) * FDIM;
    const unsigned short* wbase = Wt + ((size_t)(w * 3 * 64 + (g << 4) + r16)) * 8;

    float4 ab[4][2];   // 4-deep A buffers
    uint4  bb[4][3];   // 4-deep B buffers

    auto loadA = [&](int c, float4* dst) {
        const int k = (c << 5) + (g << 3);
        const float* src = (k < HDIM) ? (arow + k) : (hrow + (k - HDIM));
        dst[0] = *(const float4*)src;
        dst[1] = *(const float4*)(src + 4);
    };
    auto loadB = [&](int c, uint4* dst) {
        const unsigned short* p = wbase + (size_t)c * 768 * 8;
#pragma unroll
        for (int u = 0; u < 3; ++u)
            dst[u] = *(const uint4*)(p + u * 64 * 8);
    };

    f32x4 acc[3];
    const f32x4 zero = {0.0f, 0.0f, 0.0f, 0.0f};
#pragma unroll
    for (int u = 0; u < 3; ++u) acc[u] = zero;

    auto consume = [&](const float4* aA, const uint4* bB) {
        frag_cast fa;
        fa.u[0] = pack2(aA[0].x, aA[0].y);
        fa.u[1] = pack2(aA[0].z, aA[0].w);
        fa.u[2] = pack2(aA[1].x, aA[1].y);
        fa.u[3] = pack2(aA[1].z, aA[1].w);
#pragma unroll
        for (int u = 0; u < 3; ++u) {
            frag_cast fb;
            fb.u[0] = bB[u].x; fb.u[1] = bB[u].y;
            fb.u[2] = bB[u].z; fb.u[3] = bB[u].w;
            acc[u] = __builtin_amdgcn_mfma_f32_16x16x32_bf16(fa.s8, fb.s8, acc[u], 0, 0, 0);
        }
    };

    // prologue: fill 4-deep pipeline
#pragma unroll
    for (int d = 0; d < 4; ++d) { loadA(d, ab[d]); loadB(d, bb[d]); }

    // main: 6 x 4 steps (c = 0..23), static buffer names throughout
#pragma unroll
    for (int cb = 0; cb < 24; cb += 4) {
#pragma unroll
        for (int d = 0; d < 4; ++d) {
            const int c = cb + d;
            consume(ab[d], bb[d]);
            if (c + 4 < KSTEPS) { loadA(c + 4, ab[d]); loadB(c + 4, bb[d]); }
        }
    }
    consume(ab[0], bb[0]);   // c = 24

    // ---- epilogue: +b, RoPE(table), repack -> qw/kw bf16; bias_t ----
    const int bidx = m0 >> 10;
    const int s0   = m0 & (S_ - 1);
#pragma unroll
    for (int u = 0; u < 3; ++u) {
        const int tile = w * 3 + u;
        if (tile < 8) {
            const int jj  = (tile < 4 ? tile : tile - 4) * 16 + r16;
            const int fi  = jj >> 1;
            const float bvv = bv[tile * 16 + r16];
            const float sgn = (jj & 1) ? 1.0f : -1.0f;
            const float scl = (tile < 4) ? 0.125f : 1.0f;
            float x[4], p[4];
#pragma unroll
            for (int rr = 0; rr < 4; ++rr) x[rr] = acc[u][rr] + bvv;
#pragma unroll
            for (int rr = 0; rr < 4; ++rr) p[rr] = __shfl_xor(x[rr], 1, 64);
            const int cbase = (tile < 4 ? 0 : 64) + jj;
#pragma unroll
            for (int rr = 0; rr < 4; ++rr) {
                const float2 cs = rope[((s0 + g * 4 + rr) << 5) + fi];
                repack[g * 4 + rr][cbase] =
                    f2bf(fmaf(p[rr], sgn * cs.y, x[rr] * cs.x) * scl);
            }
        } else if (tile < 10) {
            const int cc = (tile - 8) * 16 + r16;
            if (cc < 18) {
                const float bvv = bv[tile * 16 + r16];
                f32x4 v;
#pragma unroll
                for (int rr = 0; rr < 4; ++rr) v[rr] = (acc[u][rr] + bvv) * 0.5f;
                *(f32x4*)(bias_t + (((size_t)(bidx * 18 + cc)) << 10) + s0 + g * 4) = v;
            }
        }
    }
    __syncthreads();
    {
        const int row = tid >> 4, seg = tid & 15;
        const uint4 v = *(const uint4*)&repack[row][seg * 8];
        if (seg < 8) *(uint4*)(qw + ((size_t)(m0 + row)) * D_ + seg * 8) = v;
        else         *(uint4*)(kw + ((size_t)(m0 + row)) * D_ + (seg - 8) * 8) = v;
    }
}

// ---------------------------------------------------------------------------
// k2: fused 64x64 QK^T via MFMA + LDS-transposed contiguous epilogue.
// (byte-identical R6/R8 -- best measured variant)
// ---------------------------------------------------------------------------
__global__ __launch_bounds__(256) void k2_logits(
    const unsigned short* __restrict__ qw, const unsigned short* __restrict__ kw,
    const float* __restrict__ bias_t, const int* __restrict__ mask,
    float* __restrict__ out)
{
    __shared__ __align__(16) char smem_u[64 * 66 * 4];
    __shared__ float bn[18][64];
    __shared__ float bm[18][64];
    __shared__ float mqf[64], mkf[64];
    unsigned short* qsm = (unsigned short*)smem_u;
    unsigned short* ksm = qsm + 64 * 64;
    float* tbuf = (float*)smem_u;

    const int tid = threadIdx.x;
    int bid;
    {
        const int i = blockIdx.x;
        bid = (i & 7) * 256 + (i >> 3);    // XCD-chunked: XCD x -> batch x
    }
    const int b   = bid >> 8;
    const int rem = bid & 255;
    const int m0  = (rem >> 4) << 6;
    const int n0  = (rem & 15) << 6;

#pragma unroll
    for (int u = 0; u < 2; ++u) {
        const int idx = tid + (u << 8);
        const int row = idx >> 3;
        const int c8  = idx & 7;
        const int sb  = (row << 7) + ((c8 ^ (row & 7)) << 4);
        const uint4 vq = *(const uint4*)(qw + ((size_t)(b << 10) + m0 + row) * D_ + (c8 << 3));
        *(uint4*)((char*)qsm + sb) = vq;
        const uint4 vk = *(const uint4*)(kw + ((size_t)(b << 10) + n0 + row) * D_ + (c8 << 3));
        *(uint4*)((char*)ksm + sb) = vk;
    }
    for (int idx = tid; idx < 18 * 64; idx += 256) {
        const int c = idx >> 6;
        const int x = idx & 63;
        bn[c][x] = bias_t[(((size_t)(b * 18 + c)) << 10) + n0 + x];
        bm[c][x] = bias_t[(((size_t)(b * 18 + c)) << 10) + m0 + x];
    }
    if (tid < 64)        mqf[tid]      = (float)mask[b * S_ + m0 + tid];
    else if (tid < 128)  mkf[tid - 64] = (float)mask[b * S_ + n0 + (tid - 64)];
    __syncthreads();

    const int lane = tid & 63;
    const int w    = tid >> 6;
    const int wr   = w >> 1;
    const int wc   = w & 1;
    const int r16  = lane & 15;
    const int g    = lane >> 4;

    f32x4 acc[2][2];
    const f32x4 zero = {0.0f, 0.0f, 0.0f, 0.0f};
#pragma unroll
    for (int mi = 0; mi < 2; ++mi)
#pragma unroll
        for (int ni = 0; ni < 2; ++ni) acc[mi][ni] = zero;

#pragma unroll
    for (int ku = 0; ku < 2; ++ku) {
        short8 af[2], bf[2];
#pragma unroll
        for (int mi = 0; mi < 2; ++mi) {
            const int row  = wr * 32 + mi * 16 + r16;
            const int slot = ((ku << 2) + g) ^ (row & 7);
            af[mi] = *(const short8*)((const char*)qsm + (row << 7) + (slot << 4));
        }
#pragma unroll
        for (int ni = 0; ni < 2; ++ni) {
            const int row  = wc * 32 + ni * 16 + r16;
            const int slot = ((ku << 2) + g) ^ (row & 7);
            bf[ni] = *(const short8*)((const char*)ksm + (row << 7) + (slot << 4));
        }
#pragma unroll
        for (int mi = 0; mi < 2; ++mi)
#pragma unroll
            for (int ni = 0; ni < 2; ++ni)
                acc[mi][ni] = __builtin_amdgcn_mfma_f32_16x16x32_bf16(
                    af[mi], bf[ni], acc[mi][ni], 0, 0, 0);
    }

    __syncthreads();
#pragma unroll
    for (int mi = 0; mi < 2; ++mi)
#pragma unroll
        for (int ni = 0; ni < 2; ++ni)
#pragma unroll
            for (int rr = 0; rr < 4; ++rr)
                tbuf[(wr * 32 + mi * 16 + g * 4 + rr) * 66 +
                     wc * 32 + ni * 16 + r16] = acc[mi][ni][rr];
    __syncthreads();

    const int rb = tid >> 4;
    const int c4 = (tid & 15) << 2;
    const float fk0 = mkf[c4 + 0], fk1 = mkf[c4 + 1],
                fk2 = mkf[c4 + 2], fk3 = mkf[c4 + 3];

    float  p[4][4], accp[4][4];
    size_t base[4];
#pragma unroll
    for (int i = 0; i < 4; ++i) {
        const int row = rb + (i << 4);
        const int rg  = m0 + row;
        const float fm = mqf[row];
        const f32x4 a = *(const f32x4*)&tbuf[row * 66 + c4];
        const float fkk[4] = {fk0, fk1, fk2, fk3};
#pragma unroll
        for (int j = 0; j < 4; ++j) {
            const float fk = fkk[j];
            const float pj = fm * fk;
            float ad = NEGV * ((1.0f - fm) * fk + (1.0f - fk));
            if (rg > n0 + c4 + j) ad += NEGV;
            p[i][j]    = pj;
            accp[i][j] = fmaf(a[j], pj, ad);
        }
        base[i] = (((size_t)(b * 9)) << 20) + ((size_t)rg << 10) + n0 + c4;
    }

#pragma unroll
    for (int t = 0; t < 9; ++t) {
        const f32x4 bnv = *(const f32x4*)&bn[2 * t][c4];
        const size_t toff = (size_t)t << 20;
#pragma unroll
        for (int i = 0; i < 4; ++i) {
            const float bmv = bm[2 * t + 1][rb + (i << 4)];
            f32x4 v;
#pragma unroll
            for (int j = 0; j < 4; ++j)
                v[j] = fmaf(bnv[j] + bmv, p[i][j], accp[i][j]);
            *(f32x4*)(out + base[i] + toff) = v;
        }
    }
}

extern "C" void kernel_launch(void* const* d_in, const int* in_sizes, int n_in,
                              void* d_out, int out_size, void* d_ws, size_t ws_size,
                              hipStream_t stream) {
    const float* lhs  = (const float*)d_in[0];
    const float* hf   = (const float*)d_in[1];
    const int*   mask = (const int*)  d_in[2];
    const float* W1   = (const float*)d_in[3];
    const float* b1   = (const float*)d_in[4];
    const float* W2   = (const float*)d_in[5];
    const float* b2   = (const float*)d_in[6];
    float* out = (float*)d_out;

    unsigned short* qw = (unsigned short*)d_ws;              // 1 MB
    unsigned short* kw = qw + (size_t)B_ * S_ * D_;          // 1 MB
    float* bias_t = (float*)((char*)d_ws + (4u << 20));      // 576 KB @ 4 MB
    unsigned short* Wt = (unsigned short*)((char*)d_ws + (8u << 20)); // 300 KB
    float* bv = (float*)((char*)d_ws + (9u << 20));          // 768 B
    float2* rope = (float2*)((char*)d_ws + (10u << 20));     // 256 KB @ 10 MB

    k0_prep<<<33, 256, 0, stream>>>(W1, b1, W2, b2, Wt, bv, rope);
    k1_proj<<<(B_ * S_) / 16, 256, 0, stream>>>(lhs, hf, Wt, bv, rope,
                                                qw, kw, bias_t);
    k2_logits<<<B_ * 16 * 16, 256, 0, stream>>>(qw, kw, bias_t, mask, out);
}